// Round 6
// baseline (3061.027 us; speedup 1.0000x reference)
//
#include <hip/hip_runtime.h>
#include <hip/hip_fp16.h>

#define TM1   127
#define NE    128
#define NT    1024
#define NB    512            // 2 batches per block, 2 blocks per CU
#define ROWW  66             // words (uint/half2) per preXh row: 64 data + 2 pad

#if __has_builtin(__builtin_amdgcn_exp2f)
#define EXP2(x) __builtin_amdgcn_exp2f(x)
#else
#define EXP2(x) exp2f(x)
#endif
#define RCP(x) __builtin_amdgcn_rcpf(x)
#define K2 2.885390081777927f   // 2*log2(e): tanh term = 1 - 2*rcp(exp2(K2*x)+1)

__device__ __forceinline__ float fast_sig(float x){ return RCP(1.0f + __expf(-x)); }
__device__ __forceinline__ float fast_tanh(float x){ float e = __expf(2.0f*x); return 1.0f - 2.0f*RCP(e+1.0f); }
__device__ __forceinline__ float blo(unsigned u){ union{unsigned i; float f;} v; v.i = u<<16;           return v.f; }
__device__ __forceinline__ float bhi(unsigned u){ union{unsigned i; float f;} v; v.i = u & 0xffff0000u; return v.f; }
__device__ __forceinline__ float rdlane(float v, int l) {
    union{float f; int i;} a, r; a.f = v;
    r.i = __builtin_amdgcn_readlane(a.i, l);   // l is wave-uniform (loop counter)
    return r.f;
}

// Pack W1dc (rows 0..255) and Wh into bf16 k-quads in workspace (same work every launch).
__global__ void pack_weights(const float* __restrict__ W1, const float* __restrict__ Wh,
                             uint2* __restrict__ W1q, uint2* __restrict__ Whq) {
    const int t = blockIdx.x*256 + threadIdx.x;
    auto bf16 = [](float f)->unsigned {
        union{float f; unsigned u;} v; v.f = f;
        return (v.u + 0x7fffu + ((v.u>>16)&1u)) >> 16;   // RNE
    };
    if (t < 8192) {                       // W1q[k4][e], k4=0..63 covers k=0..255 ([d;c])
        const int k4 = t >> 7, e = t & 127;
        unsigned a = bf16(W1[(4*k4+0)*NE + e]);
        unsigned b = bf16(W1[(4*k4+1)*NE + e]);
        unsigned c = bf16(W1[(4*k4+2)*NE + e]);
        unsigned d = bf16(W1[(4*k4+3)*NE + e]);
        W1q[k4*128 + e] = make_uint2(a | (b<<16), c | (d<<16));
    } else if (t < 24576) {               // Whq[k4][j], k4=0..31 covers k=0..127
        const int t2 = t - 8192;
        const int k4 = t2 >> 9, j = t2 & 511;
        unsigned a = bf16(Wh[(4*k4+0)*512 + j]);
        unsigned b = bf16(Wh[(4*k4+1)*512 + j]);
        unsigned c = bf16(Wh[(4*k4+2)*512 + j]);
        unsigned d = bf16(Wh[(4*k4+3)*512 + j]);
        Whq[k4*512 + j] = make_uint2(a | (b<<16), c | (d<<16));
    }
}

__global__ __launch_bounds__(NT)
void decoder_kernel(const float* __restrict__ Xg,     // (1024,127,128)
                    const float* __restrict__ yprev,  // (1024,127)
                    const float* __restrict__ W1,     // (384,128)
                    const float* __restrict__ b1,
                    const float* __restrict__ W2,     // (128)
                    const float* __restrict__ b2v,
                    const float* __restrict__ Wfc,    // (129)
                    const float* __restrict__ bfcv,
                    const float* __restrict__ Wx,     // (512)
                    const float* __restrict__ blv,    // (512)
                    const float* __restrict__ Wf,     // (256)
                    const float* __restrict__ bfv,
                    const uint2* __restrict__ W1q,    // packed bf16 [64][128]
                    const uint2* __restrict__ Whq,    // packed bf16 [32][512]
                    float* __restrict__ out)          // (1024)
{
    __shared__ __align__(16) unsigned preXu[2*128*ROWW]; // 67584 B: fp16 K2*(b1+X@W1x), 2B pad/row
    __shared__ __align__(16) float sdc  [512];           // [b*256 + (d:0..127 | c:128..255)]
    __shared__ __align__(16) unsigned uwhu[2*136];       // [b*136+q*34+j]: half2(K2*u, -2*W2)
    __shared__ __align__(16) float w2m2 [128];
    __shared__ __align__(16) float zsc  [1024];          // [b*512+j] d@Wh; staging / epilogue scratch
    __shared__ __align__(16) float XWfcs[256];
    __shared__ __align__(16) float betas[256];
    __shared__ __align__(16) float ys   [256];
    __shared__ __align__(16) uint2 wxq  [128];           // bf16 Wx quads (i,f,g,o)
    __shared__ __align__(16) uint2 blq  [128];           // bf16 bl quads
    __shared__ float params[8];                          // 0:wfcy 1:bfc 2:bf 4..7:pinit[q]
    __shared__ float swv[16];

    const int tid  = (int)threadIdx.x;
    const int lane = tid & 63;
    const int b0   = (int)blockIdx.x * 2;
    const int eA = tid >> 3, oA = tid & 7;                      // A + preamble
    const int wbC = tid >> 9, jC = tid & 511;                   // C (wave-uniform batch)
    const int bB = tid >> 9, tB = (tid >> 2) & 127, qB = tid & 3; // B
    const int wv = tid >> 6;

    auto bf16r = [](float f)->unsigned {
        union{float f; unsigned u;} v; v.f = f;
        return (v.u + 0x7fffu + ((v.u>>16)&1u)) >> 16;
    };

    // ---- init (nothing loop-persistent in VGPRs) ----
    if (tid < 128) {
        w2m2[tid] = -2.0f * W2[tid];
        wxq[tid] = make_uint2(bf16r(Wx[tid])     | (bf16r(Wx[128+tid])<<16),
                              bf16r(Wx[256+tid]) | (bf16r(Wx[384+tid])<<16));
        blq[tid] = make_uint2(bf16r(blv[tid])     | (bf16r(blv[128+tid])<<16),
                              bf16r(blv[256+tid]) | (bf16r(blv[384+tid])<<16));
    }
    if (tid == 0) { params[0] = Wfc[NE]; params[1] = bfcv[0]; params[2] = bfv[0]; }
    if (tid >= 4 && tid < 8) {                       // pinit[q] = b2/4 + sum W2[q-slice]
        const int q = tid - 4;
        float s = b2v[0] * 0.25f;
        for (int i = 0; i < 32; ++i) s += W2[q*32 + i];
        params[4 + q] = s;
    }
    if (tid < 512) {
        const int b = tid >> 8, g = tid & 255;
        sdc[b*256 + g] = Xg[(size_t)(b0+b)*TM1*NE];  // d0 = c0 = X[b,0,0]
    }
    if (tid < 256) {
        const int b = tid >> 7, g = tid & 127;
        ys[tid] = (g < TM1) ? yprev[(size_t)(b0+b)*TM1 + g] : 0.0f;
        float xw = 0.0f;                              // XWfc[t'] = X[t'].Wfc[:128]
        if (g < TM1) {
            const float4* xr = (const float4*)(Xg + ((size_t)(b0+b)*TM1 + g)*NE);
            #pragma unroll 4
            for (int i = 0; i < 32; ++i) {
                const float4 x = xr[i];
                const float4 w = *(const float4*)&Wfc[i*4];
                xw = fmaf(x.x,w.x, fmaf(x.y,w.y, fmaf(x.z,w.z, fmaf(x.w,w.w, xw))));
            }
        }
        XWfcs[tid] = xw;                              // row 127 -> 0
    }

    // ---- preamble: preX fp16, via LDS-staged X chunks (8 rows at a time in zsc) ----
    {
        float w1x[16];                                // k-quads in rotated read order
        #pragma unroll
        for (int q4 = 0; q4 < 4; ++q4) {
            const int qq = (q4 + oA) & 3;
            #pragma unroll
            for (int m = 0; m < 4; ++m)
                w1x[q4*4+m] = W1[(256 + oA*16 + qq*4 + m)*NE + eA];
        }
        const float b1r = b1[eA];
        __half* preXhh = (__half*)preXu;
        for (int b = 0; b < 2; ++b) {
            const float* Xbase = Xg + (size_t)(b0+b)*TM1*NE;
            for (int ch = 0; ch < 16; ++ch) {
                __syncthreads();                      // zsc free?
                {   const int rr = tid >> 7, kk = tid & 127;
                    const int tp = ch*8 + rr;
                    zsc[tid] = (tp < TM1) ? Xbase[tp*NE + kk] : 0.0f; }
                __syncthreads();
                #pragma unroll 2
                for (int rr = 0; rr < 8; ++rr) {
                    float s = 0.0f;
                    #pragma unroll
                    for (int q4 = 0; q4 < 4; ++q4) {
                        const int qq = (q4 + oA) & 3;
                        const float4 x = *(const float4*)&zsc[rr*128 + oA*16 + qq*4];
                        s = fmaf(w1x[q4*4+0], x.x, fmaf(w1x[q4*4+1], x.y,
                            fmaf(w1x[q4*4+2], x.z, fmaf(w1x[q4*4+3], x.w, s))));
                    }
                    s += __shfl_xor(s,1); s += __shfl_xor(s,2); s += __shfl_xor(s,4);
                    if (oA == 0)                      // row 127 gets finite K2*b1 (never used)
                        preXhh[(b*128 + ch*8 + rr)*(2*ROWW) + eA] = __float2half(K2*(s + b1r));
                }
            }
        }
    }
    __syncthreads();

    const float4* sdc4 = (const float4*)sdc;

    for (int t = 0; t < TM1; ++t) {
        // ==== A: u[b][e], 8-way k-split; rotated quads -> all 32 banks, 8-lane bcast ====
        {
            float a0 = 0.f, a1 = 0.f;
            #pragma unroll 4
            for (int i = 0; i < 8; ++i) {
                const int k4 = oA*8 + ((i + oA) & 7);
                const uint2 w = W1q[k4*128 + eA];
                const float wa=blo(w.x), wb=bhi(w.x), wc=blo(w.y), wd=bhi(w.y);
                const float4 v0 = sdc4[k4];
                const float4 v1 = sdc4[64 + k4];
                a0 = fmaf(wa,v0.x,fmaf(wb,v0.y,fmaf(wc,v0.z,fmaf(wd,v0.w,a0))));
                a1 = fmaf(wa,v1.x,fmaf(wb,v1.y,fmaf(wc,v1.z,fmaf(wd,v1.w,a1))));
            }
            a0 += __shfl_xor(a0,1); a0 += __shfl_xor(a0,2); a0 += __shfl_xor(a0,4);
            a1 += __shfl_xor(a1,1); a1 += __shfl_xor(a1,2); a1 += __shfl_xor(a1,4);
            if (oA == 0) {
                const float w2e = w2m2[eA];
                const int ui = (eA >> 5)*34 + (eA & 31);
                __half2 h0 = __floats2half2_rn(K2*a0, w2e);
                __half2 h1 = __floats2half2_rn(K2*a1, w2e);
                uwhu[ui]       = *(unsigned*)&h0;
                uwhu[136 + ui] = *(unsigned*)&h1;
            }
        }
        // ==== C: z[b][j] = d@Wh, LDS-free via wave-uniform readlane broadcast ====
        {
            const float dv0 = sdc[wbC*256 + lane];        // d[0..63]
            const float dv1 = sdc[wbC*256 + 64 + lane];   // d[64..127]
            float z = 0.f;
            #pragma unroll 4
            for (int k4 = 0; k4 < 16; ++k4) {
                const uint2 w = Whq[k4*512 + jC];
                const int k = 4*k4;
                z = fmaf(blo(w.x), rdlane(dv0, k+0), z);
                z = fmaf(bhi(w.x), rdlane(dv0, k+1), z);
                z = fmaf(blo(w.y), rdlane(dv0, k+2), z);
                z = fmaf(bhi(w.y), rdlane(dv0, k+3), z);
            }
            #pragma unroll 4
            for (int k4 = 16; k4 < 32; ++k4) {
                const uint2 w = Whq[k4*512 + jC];
                const int k = 4*k4 - 64;
                z = fmaf(blo(w.x), rdlane(dv1, k+0), z);
                z = fmaf(bhi(w.x), rdlane(dv1, k+1), z);
                z = fmaf(blo(w.y), rdlane(dv1, k+2), z);
                z = fmaf(bhi(w.y), rdlane(dv1, k+3), z);
            }
            zsc[wbC*512 + jC] = z;
        }
        __syncthreads();                                   // S1

        // ==== B: beta[b][t'] quarter-rows; imm-offset b32 preX reads, b64 uwh reads ====
        {
            const unsigned* rowp = preXu + (bB*128 + tB)*ROWW + qB*16;
            const unsigned* uwp  = uwhu + bB*136 + qB*34;
            float pb = params[4 + qB];
            #pragma unroll 4
            for (int i = 0; i < 16; ++i) {
                const unsigned pw = rowp[i];
                const uint2 uu = *(const uint2*)&uwp[2*i];
                const __half2 px2 = *(const __half2*)&pw;
                const __half2 u0  = *(const __half2*)&uu.x;  // (K2u, -2W2) for e=q*32+2i
                const __half2 u1  = *(const __half2*)&uu.y;  // e=q*32+2i+1
                pb = fmaf(__high2float(u0),
                          RCP(EXP2(__low2float(px2)  + __low2float(u0)) + 1.0f), pb);
                pb = fmaf(__high2float(u1),
                          RCP(EXP2(__high2float(px2) + __low2float(u1)) + 1.0f), pb);
            }
            pb += __shfl_xor(pb,1); pb += __shfl_xor(pb,2);  // sum over 4 quarters
            if (t == TM1-1 && qB == 0) betas[bB*128 + tB] = pb;
            float prod = pb * XWfcs[bB*128 + tB];            // row 127 -> *0
            prod += __shfl_xor(prod,4);  prod += __shfl_xor(prod,8);
            prod += __shfl_xor(prod,16); prod += __shfl_xor(prod,32);
            if ((tid & 63) == 0) swv[wv] = prod;
        }
        __syncthreads();                                   // S2

        // ==== gates (256 threads) ====
        if (tid < 256) {
            const int b = tid >> 7, g = tid & 127;
            const float ssum = ((swv[b*8+0]+swv[b*8+1])+(swv[b*8+2]+swv[b*8+3]))
                             + ((swv[b*8+4]+swv[b*8+5])+(swv[b*8+6]+swv[b*8+7]));
            const float ytl = fmaf(ys[b*128 + t], params[0], ssum + params[1]);
            const uint2 wq = wxq[g], bq = blq[g];
            const float zi = fmaf(ytl, blo(wq.x), blo(bq.x)) + zsc[b*512 +       g];
            const float zf = fmaf(ytl, bhi(wq.x), bhi(bq.x)) + zsc[b*512 + 128 + g];
            const float zg = fmaf(ytl, blo(wq.y), blo(bq.y)) + zsc[b*512 + 256 + g];
            const float zo = fmaf(ytl, bhi(wq.y), bhi(bq.y)) + zsc[b*512 + 384 + g];
            const float c_old = sdc[b*256 + 128 + g];
            const float cn = fast_sig(zf)*c_old + fast_sig(zi)*fast_tanh(zg);
            const float dn = fast_sig(zo)*fast_tanh(cn);
            sdc[b*256 + g] = dn; sdc[b*256 + 128 + g] = cn;
        }
        __syncthreads();                                   // S3
    }

    // ---- epilogue: final ctx from betas + global X, then out ----
    if (tid < 256) {
        const int b = tid >> 7, e = tid & 127;
        const float* Xb = Xg + (size_t)(b0+b)*TM1*NE + e;
        float cacc = 0.0f;
        #pragma unroll 4
        for (int tp = 0; tp < TM1; ++tp)
            cacc = fmaf(betas[b*128 + tp], Xb[(size_t)tp*NE], cacc);
        zsc[tid] = fmaf(sdc[b*256 + e], Wf[e], cacc * Wf[128 + e]);
    }
    __syncthreads();
    if (tid < 2) {
        float s = 0.0f;
        for (int i = 0; i < 128; ++i) s += zsc[tid*128 + i];
        out[b0 + tid] = s + params[2];
    }
}

extern "C" void kernel_launch(void* const* d_in, const int* in_sizes, int n_in,
                              void* d_out, int out_size, void* d_ws, size_t ws_size,
                              hipStream_t stream) {
    (void)in_sizes; (void)n_in; (void)ws_size; (void)out_size;
    const float* Xg    = (const float*)d_in[0];
    const float* yprev = (const float*)d_in[1];
    const float* W1    = (const float*)d_in[2];
    const float* b1    = (const float*)d_in[3];
    const float* W2    = (const float*)d_in[4];
    const float* b2    = (const float*)d_in[5];
    const float* Wfc   = (const float*)d_in[6];
    const float* bfc   = (const float*)d_in[7];
    const float* Wx    = (const float*)d_in[8];
    const float* Wh    = (const float*)d_in[9];
    const float* bl    = (const float*)d_in[10];
    const float* Wf    = (const float*)d_in[11];
    const float* bf    = (const float*)d_in[12];

    uint2* W1q = (uint2*)d_ws;                         // 64 KB
    uint2* Whq = (uint2*)((char*)d_ws + 65536);        // 128 KB

    pack_weights<<<96, 256, 0, stream>>>(W1, Wh, W1q, Whq);
    decoder_kernel<<<NB, NT, 0, stream>>>(
        Xg, yprev, W1, b1, W2, b2, Wfc, bfc, Wx, bl, Wf, bf, W1q, Whq, (float*)d_out);
}